// Round 4
// baseline (427.951 us; speedup 1.0000x reference)
//
#include <hip/hip_runtime.h>
#include <cstdint>
#include <cstddef>

#define M_DIM 4096
#define N_DIM 8192
#define K_DIM 4096

typedef __attribute__((ext_vector_type(4))) int int4v;

// ---------------------------------------------------------------------------
// Pack int32 (values 0..126) -> int8 in MFMA-fragment order.
// Contract: p = panel (16 rows), s = kstep (64 B), lane l in [0,64):
//   dst[((p*64 + s)*64 + l)*16 + b] = src[16p + (l&15)][64s + (l>>4)*16 + b]
// Thread t handles 4 consecutive k-elements of one row:
//   16 B coalesced int4 read, one 4 B write into the fragment layout.
// ---------------------------------------------------------------------------
__global__ void __launch_bounds__(256) pack_frag(const int* __restrict__ a,
                                                 const int* __restrict__ b,
                                                 unsigned char* __restrict__ pa,
                                                 unsigned char* __restrict__ pb) {
    size_t t = (size_t)blockIdx.x * 256 + threadIdx.x;
    const size_t NA = (size_t)M_DIM * (K_DIM / 4);
    const int* __restrict__ src;
    unsigned char* __restrict__ dst;
    if (t < NA) {
        src = a; dst = pa;
    } else {
        src = b; dst = pb; t -= NA;
    }
    const int r = (int)(t >> 10);       // row
    const int g = (int)(t & 1023);      // 4-elem group within row
    int4v v = *(const int4v*)(src + (size_t)r * K_DIM + 4 * g);
    const int w = (v[0] & 0xff) | ((v[1] & 0xff) << 8) | ((v[2] & 0xff) << 16) | (v[3] << 24);
    const int p = r >> 4, lr = r & 15;
    const int s = g >> 4, q = (g >> 2) & 3, bo = (g & 3) * 4;
    const size_t off = ((size_t)(p * 64 + s) * 64 + (lr + 16 * q)) * 16 + bo;
    *(int*)(dst + off) = w;
}

// ---------------------------------------------------------------------------
// GEMM: block tile 256(M) x 128(N), 256 thr = 2x2 waves, wave tile 128x64.
// mfma_i32_16x16x64_i8 (verified layout). A: direct fragment-ordered global
// loads (no LDS). B: LDS double-buffered via global_load_lds, ONE barrier
// per 128 K-bytes, 64 MFMA per wave per barrier.
// ---------------------------------------------------------------------------
__device__ inline void async_copy16(const unsigned char* g, unsigned char* l) {
    __builtin_amdgcn_global_load_lds(
        (const __attribute__((address_space(1))) void*)g,
        (__attribute__((address_space(3))) void*)l,
        16, 0, 0);
}

__global__ void __launch_bounds__(256, 2) gemm_i8(const unsigned char* __restrict__ Ap,
                                                  const unsigned char* __restrict__ Bp,
                                                  const _Float16* __restrict__ arow,
                                                  const _Float16* __restrict__ acol,
                                                  _Float16* __restrict__ Cout) {
    __shared__ __align__(16) unsigned char Bs[2 * 16384];  // double buffer

    const int tid  = threadIdx.x;
    const int lane = tid & 63;
    const int wave = tid >> 6;
    const int bm   = blockIdx.x;  // 0..15  (256 rows each)
    const int bn   = blockIdx.y;  // 0..63  (128 cols each)

    const int wmp = (wave & 1) * 8;   // A panel offset within block (8 panels = 128 rows)
    const int wnp = (wave >> 1) * 4;  // B panel offset within block (4 panels = 64 cols)

    // A fragment base: panel (bm*16 + wmp + i), kstep byte offset gk + h*1024
    const unsigned char* Abase = Ap + (size_t)(bm * 16 + wmp) * 65536 + lane * 16;

    // B staging: 4 rounds x 16 B/thread = 16 KB/tile. LDS layout:
    // [panel (wnp+j)] * 2048 + [h] * 1024 + lane*16.
    const size_t Bblk = (size_t)bn * 8 * 65536;
    const unsigned char* bg[4];
    int blo[4];
#pragma unroll
    for (int r = 0; r < 4; ++r) {
        const int offu = r * 4096 + wave * 1024;
        bg[r]  = Bp + Bblk + (size_t)(offu >> 11) * 65536 + (offu & 2047) + lane * 16;
        blo[r] = offu;  // wave-uniform LDS offset; HW adds lane*16
    }
    const int bf_base = wnp * 2048 + lane * 16;

    int4v acc[8][4];
#pragma unroll
    for (int i = 0; i < 8; ++i)
#pragma unroll
        for (int j = 0; j < 4; ++j) acc[i][j] = (int4v)0;

    // prologue: stage tile 0 into buffer 0
#pragma unroll
    for (int r = 0; r < 4; ++r) async_copy16(bg[r], Bs + blo[r]);
    __syncthreads();

    for (int T = 0; T < K_DIM / 128; ++T) {
        const int cur = (T & 1) * 16384;
        const int nxt = 16384 - cur;
        const int gk  = T * 2048;

        // A fragments FIRST (oldest in vmcnt FIFO -> waiting on them does not
        // drain the B stage issued below).
        int4v af[2][8];
#pragma unroll
        for (int h = 0; h < 2; ++h)
#pragma unroll
            for (int i = 0; i < 8; ++i)
                af[h][i] = *(const int4v*)(Abase + (size_t)i * 65536 + gk + h * 1024);

        // prefetch next B tile into the other buffer (no wait here)
        if (T < K_DIM / 128 - 1) {
#pragma unroll
            for (int r = 0; r < 4; ++r)
                async_copy16(bg[r] + gk + 2048, Bs + nxt + blo[r]);
        }

#pragma unroll
        for (int h = 0; h < 2; ++h) {
            int4v bf[4];
#pragma unroll
            for (int j = 0; j < 4; ++j)
                bf[j] = *(const int4v*)(Bs + cur + bf_base + j * 2048 + h * 1024);
#pragma unroll
            for (int i = 0; i < 8; ++i)
#pragma unroll
                for (int j = 0; j < 4; ++j)
                    acc[i][j] = __builtin_amdgcn_mfma_i32_16x16x64_i8(af[h][i], bf[j],
                                                                      acc[i][j], 0, 0, 0);
        }
        __syncthreads();  // single barrier: next stage had full compute phase to land
    }

    // --- epilogue: C/D layout col=lane&15, row=(lane>>4)*4+reg (verified)
    const int gcol0 = bn * 128 + wnp * 16 + (lane & 15);
    float ac4[4];
#pragma unroll
    for (int j = 0; j < 4; ++j) ac4[j] = (float)acol[gcol0 + j * 16];

    const size_t grow0 = (size_t)bm * 256 + wmp * 16 + (lane >> 4) * 4;
#pragma unroll
    for (int i = 0; i < 8; ++i) {
#pragma unroll
        for (int r = 0; r < 4; ++r) {
            const size_t row = grow0 + i * 16 + r;
            const float ar = (float)arow[row];
            _Float16* outp = Cout + row * (size_t)N_DIM + gcol0;
#pragma unroll
            for (int j = 0; j < 4; ++j) {
                float v = (float)acc[i][j][r] * ar * ac4[j];
                outp[j * 16] = (_Float16)v;
            }
        }
    }
}

// ---------------------------------------------------------------------------
extern "C" void kernel_launch(void* const* d_in, const int* in_sizes, int n_in,
                              void* d_out, int out_size, void* d_ws, size_t ws_size,
                              hipStream_t stream) {
    const int* a = (const int*)d_in[0];             // [M,K] int32 (int8 values)
    const int* b = (const int*)d_in[1];             // [N,K] int32 (int8 values)
    const _Float16* ar = (const _Float16*)d_in[2];  // [M] fp16
    const _Float16* ac = (const _Float16*)d_in[3];  // [N] fp16
    _Float16* out = (_Float16*)d_out;               // [M,N] fp16

    unsigned char* pa = (unsigned char*)d_ws;        // 16 MB
    unsigned char* pb = pa + (size_t)M_DIM * K_DIM;  // 32 MB

    const size_t groups = ((size_t)M_DIM + N_DIM) * (K_DIM / 4);
    pack_frag<<<(int)(groups / 256), 256, 0, stream>>>(a, b, pa, pb);

    dim3 grid(M_DIM / 256, N_DIM / 128);
    gemm_i8<<<grid, 256, 0, stream>>>(pa, pb, ar, ac, out);
}

// Round 5
// 401.511 us; speedup vs baseline: 1.0658x; 1.0658x over previous
//
#include <hip/hip_runtime.h>
#include <cstdint>
#include <cstddef>

#define M_DIM 4096
#define N_DIM 8192
#define K_DIM 4096

typedef __attribute__((ext_vector_type(4))) int int4v;

// ---------------------------------------------------------------------------
// Pack into MFMA-fragment order (int32 -> int8). R3-verified version.
// Layout: 16-row panels; kstep = 64 K-bytes; chunk(p,s) = 1024 B where
// lane l holds row 16p+(l&15), k-bytes s*64 + (l>>4)*16 .. +16.
// Panel stride = 16*K = 65536 B. One thread = one 16B lane-fragment:
// 4x dwordx4 reads, one 16B coalesced write.
// ---------------------------------------------------------------------------
__global__ void __launch_bounds__(256) pack_frag(const int* __restrict__ a,
                                                 const int* __restrict__ b,
                                                 unsigned char* __restrict__ pa,
                                                 unsigned char* __restrict__ pb) {
    size_t t = (size_t)blockIdx.x * 256 + threadIdx.x;
    const size_t NA = (size_t)(M_DIM / 16) * (K_DIM / 64) * 64;
    const int* __restrict__ src;
    unsigned char* __restrict__ dst;
    if (t < NA) {
        src = a; dst = pa;
    } else {
        src = b; dst = pb; t -= NA;
    }
    const int l = (int)(t & 63);
    const int s = (int)((t >> 6) & 63);
    const int p = (int)(t >> 12);
    const int* g = src + ((size_t)(16 * p + (l & 15))) * K_DIM + s * 64 + (l >> 4) * 16;
    const int4v* g4 = (const int4v*)g;
    int4v o;
#pragma unroll
    for (int q = 0; q < 4; ++q) {
        int4v v = g4[q];
        o[q] = (v[0] & 0xff) | ((v[1] & 0xff) << 8) | ((v[2] & 0xff) << 16) | (v[3] << 24);
    }
    ((int4v*)dst)[t] = o;
}

// ---------------------------------------------------------------------------
// GEMM: 128x128 block, 256 thr = 2x2 waves of 64x64, mfma_i32_16x16x64_i8.
// A: direct fragment-ordered global loads, REGISTER-PREFETCHED one K-iter
// ahead (ping-pong af[2]) so no load latency sits on the MFMA path.
// B: LDS double-buffered via global_load_lds (prefetched one iter ahead),
// ONE barrier per 128 K-bytes; ds_read_b128 at base+lane*16, conflict-free.
// ---------------------------------------------------------------------------
__device__ inline void async_copy16(const unsigned char* g, unsigned char* l) {
    __builtin_amdgcn_global_load_lds(
        (const __attribute__((address_space(1))) void*)g,
        (__attribute__((address_space(3))) void*)l,
        16, 0, 0);
}

__global__ void __launch_bounds__(256, 2) gemm_i8(const unsigned char* __restrict__ Ap,
                                                  const unsigned char* __restrict__ Bp,
                                                  const _Float16* __restrict__ arow,
                                                  const _Float16* __restrict__ acol,
                                                  _Float16* __restrict__ Cout) {
    __shared__ __align__(16) unsigned char Bs[2 * 16384];  // double buffer

    const int tid  = threadIdx.x;
    const int lane = tid & 63;
    const int wave = tid >> 6;
    const int bn   = blockIdx.x;  // 0..63
    const int bm   = blockIdx.y;  // 0..31

    const int wm = (wave & 1) * 64;   // wave row offset in 128-tile
    const int wn = (wave >> 1) * 64;  // wave col offset in 128-tile

    // A fragment base: panel (bm*8 + wm/16 + i), + T*2048 + h*1024 + lane*16
    const unsigned char* Abase = Ap + (size_t)(bm * 8 + (wm >> 4)) * 65536 + lane * 16;

    // B staging: 4 rounds x 16 B/thread = 16 KB/tile (linear chunk order).
    const size_t Bblk = (size_t)bn * 8 * 65536;
    const unsigned char* bg[4];
    int blo[4];
#pragma unroll
    for (int r = 0; r < 4; ++r) {
        const int offu = r * 4096 + wave * 1024;
        bg[r]  = Bp + Bblk + (size_t)(offu >> 11) * 65536 + (offu & 2047) + lane * 16;
        blo[r] = offu;  // wave-uniform; HW adds lane*16
    }
    const int bf_base = ((wn >> 4) << 11) + lane * 16;  // + j*2048 + h*1024

    int4v acc[4][4];
#pragma unroll
    for (int i = 0; i < 4; ++i)
#pragma unroll
        for (int j = 0; j < 4; ++j) acc[i][j] = (int4v)0;

    const int NT = K_DIM / 128;  // 32
    int4v af[2][2][4];           // [pingpong][kstep h][panel i]

    // prologue: A(0) into af[0], B(0) into buffer 0
#pragma unroll
    for (int h = 0; h < 2; ++h)
#pragma unroll
        for (int i = 0; i < 4; ++i)
            af[0][h][i] = *(const int4v*)(Abase + (size_t)i * 65536 + h * 1024);
#pragma unroll
    for (int r = 0; r < 4; ++r) async_copy16(bg[r], Bs + blo[r]);
    __syncthreads();

#pragma unroll 2
    for (int T = 0; T < NT; ++T) {
        const int pp = T & 1;
        const int gkn = (T + 1) * 2048;

        if (T + 1 < NT) {
            // A prefetch for T+1 (issued first: oldest in vmcnt FIFO)
#pragma unroll
            for (int h = 0; h < 2; ++h)
#pragma unroll
                for (int i = 0; i < 4; ++i)
                    af[pp ^ 1][h][i] =
                        *(const int4v*)(Abase + (size_t)i * 65536 + gkn + h * 1024);
            // B prefetch for T+1 into the other LDS buffer
#pragma unroll
            for (int r = 0; r < 4; ++r)
                async_copy16(bg[r] + gkn, Bs + (pp ^ 1) * 16384 + blo[r]);
        }

        const unsigned char* Bcur = Bs + pp * 16384;
#pragma unroll
        for (int h = 0; h < 2; ++h) {
            int4v bf[4];
#pragma unroll
            for (int j = 0; j < 4; ++j)
                bf[j] = *(const int4v*)(Bcur + bf_base + j * 2048 + h * 1024);
#pragma unroll
            for (int i = 0; i < 4; ++i)
#pragma unroll
                for (int j = 0; j < 4; ++j)
                    acc[i][j] = __builtin_amdgcn_mfma_i32_16x16x64_i8(af[pp][h][i], bf[j],
                                                                      acc[i][j], 0, 0, 0);
        }
        __syncthreads();  // drains prefetches issued ~640 SIMD-cycles earlier
    }

    // --- epilogue: C/D layout col=lane&15, row=(lane>>4)*4+reg (verified)
    const int gcol0 = bn * 128 + wn + (lane & 15);
    float ac4[4];
#pragma unroll
    for (int j = 0; j < 4; ++j) ac4[j] = (float)acol[gcol0 + j * 16];

    const size_t grow0 = (size_t)bm * 128 + wm + (lane >> 4) * 4;
#pragma unroll
    for (int i = 0; i < 4; ++i) {
#pragma unroll
        for (int r = 0; r < 4; ++r) {
            const size_t row = grow0 + i * 16 + r;
            const float ar = (float)arow[row];
            _Float16* outp = Cout + row * (size_t)N_DIM + gcol0;
#pragma unroll
            for (int j = 0; j < 4; ++j) {
                float v = (float)acc[i][j][r] * ar * ac4[j];
                outp[j * 16] = (_Float16)v;
            }
        }
    }
}

// ---------------------------------------------------------------------------
extern "C" void kernel_launch(void* const* d_in, const int* in_sizes, int n_in,
                              void* d_out, int out_size, void* d_ws, size_t ws_size,
                              hipStream_t stream) {
    const int* a = (const int*)d_in[0];             // [M,K] int32 (int8 values)
    const int* b = (const int*)d_in[1];             // [N,K] int32 (int8 values)
    const _Float16* ar = (const _Float16*)d_in[2];  // [M] fp16
    const _Float16* ac = (const _Float16*)d_in[3];  // [N] fp16
    _Float16* out = (_Float16*)d_out;               // [M,N] fp16

    unsigned char* pa = (unsigned char*)d_ws;        // 16 MB
    unsigned char* pb = pa + (size_t)M_DIM * K_DIM;  // 32 MB

    const size_t total_frag = (size_t)(M_DIM / 16 + N_DIM / 16) * (K_DIM / 64) * 64;
    pack_frag<<<(int)(total_frag / 256), 256, 0, stream>>>(a, b, pa, pb);

    dim3 grid(N_DIM / 128, M_DIM / 128);
    gemm_i8<<<grid, 256, 0, stream>>>(pa, pb, ar, ac, out);
}

// Round 6
// 382.421 us; speedup vs baseline: 1.1191x; 1.0499x over previous
//
#include <hip/hip_runtime.h>
#include <cstdint>
#include <cstddef>

#define M_DIM 4096
#define N_DIM 8192
#define K_DIM 4096

typedef __attribute__((ext_vector_type(4))) int int4v;

// ---------------------------------------------------------------------------
// Pack into MFMA-fragment order (int32 -> int8). R3-verified, byte-identical.
// p = 16-row panel, s = 64-byte kstep, lane l: chunk(p,s) is 1024 B where
// lane l holds row 16p+(l&15), k-bytes s*64 + (l>>4)*16 .. +16.
// ---------------------------------------------------------------------------
__global__ void __launch_bounds__(256) pack_frag(const int* __restrict__ a,
                                                 const int* __restrict__ b,
                                                 unsigned char* __restrict__ pa,
                                                 unsigned char* __restrict__ pb) {
    size_t t = (size_t)blockIdx.x * 256 + threadIdx.x;
    const size_t NA = (size_t)(M_DIM / 16) * (K_DIM / 64) * 64;
    const int* __restrict__ src;
    unsigned char* __restrict__ dst;
    if (t < NA) {
        src = a; dst = pa;
    } else {
        src = b; dst = pb; t -= NA;
    }
    const int l = (int)(t & 63);
    const int s = (int)((t >> 6) & 63);
    const int p = (int)(t >> 12);
    const int* g = src + ((size_t)(16 * p + (l & 15))) * K_DIM + s * 64 + (l >> 4) * 16;
    const int4v* g4 = (const int4v*)g;
    int4v o;
#pragma unroll
    for (int q = 0; q < 4; ++q) {
        int4v v = g4[q];
        o[q] = (v[0] & 0xff) | ((v[1] & 0xff) << 8) | ((v[2] & 0xff) << 16) | (v[3] << 24);
    }
    ((int4v*)dst)[t] = o;
}

// ---------------------------------------------------------------------------
// GEMM: block tile 256(M) x 256(N), 512 thr = 8 waves, wave tile 64x128
// (4 A-panels x 8 B-panels). mfma_i32_16x16x64_i8, verified layouts.
// Both A and B staged ONCE per block into LDS (no duplicate wave-level
// global reads): VMEM traffic 1 GB total vs 3 GB in R5.
// BK=64: per iter stage 32 KB (2 async_copy16/thread), double-buffered
// (4 x 16 KB = 64 KB LDS), ONE barrier per iter, stage(T+1) issued before
// compute(T) so the barrier's vmcnt(0) drain waits on ~1300-cycle-old loads.
// ---------------------------------------------------------------------------
__device__ inline void async_copy16(const unsigned char* g, unsigned char* l) {
    __builtin_amdgcn_global_load_lds(
        (const __attribute__((address_space(1))) void*)g,
        (__attribute__((address_space(3))) void*)l,
        16, 0, 0);
}

__global__ void __launch_bounds__(512, 2) gemm_i8(const unsigned char* __restrict__ Ap,
                                                  const unsigned char* __restrict__ Bp,
                                                  const _Float16* __restrict__ arow,
                                                  const _Float16* __restrict__ acol,
                                                  _Float16* __restrict__ Cout) {
    __shared__ __align__(16) unsigned char As[2 * 16384];  // 16 panels x 1 KB, x2 buf
    __shared__ __align__(16) unsigned char Bs[2 * 16384];

    const int tid  = threadIdx.x;
    const int lane = tid & 63;
    const int wave = tid >> 6;        // 0..7
    const int bn   = blockIdx.x;      // 0..31 (256 cols each)
    const int bm   = blockIdx.y;      // 0..15 (256 rows each)

    const int pm0 = (wave & 3) * 4;   // A panel base within block (4 panels = 64 rows)
    const int pn0 = (wave >> 2) * 8;  // B panel base within block (8 panels = 128 cols)

    // staging: wave w stages A panels {2w, 2w+1} and B panels {2w, 2w+1}.
    // global chunk for (panel p, kstep T): base + (p_glob*64 + T)*1024 + lane*16.
    const unsigned char* ag[2];
    const unsigned char* bg[2];
    int slo[2];
#pragma unroll
    for (int r = 0; r < 2; ++r) {
        const int p = 2 * wave + r;
        ag[r]  = Ap + ((size_t)(bm * 16 + p) * 64) * 1024 + lane * 16;
        bg[r]  = Bp + ((size_t)(bn * 16 + p) * 64) * 1024 + lane * 16;
        slo[r] = p * 1024;  // wave-uniform LDS offset; HW adds lane*16
    }

    const int a_off = pm0 * 1024 + lane * 16;  // + i*1024
    const int b_off = pn0 * 1024 + lane * 16;  // + j*1024

    int4v acc[4][8];
#pragma unroll
    for (int i = 0; i < 4; ++i)
#pragma unroll
        for (int j = 0; j < 8; ++j) acc[i][j] = (int4v)0;

    const int NT = K_DIM / 64;  // 64

    // prologue: stage T=0 into buffer 0
#pragma unroll
    for (int r = 0; r < 2; ++r) {
        async_copy16(ag[r], As + slo[r]);
        async_copy16(bg[r], Bs + slo[r]);
    }
    __syncthreads();

#pragma unroll 2
    for (int T = 0; T < NT; ++T) {
        const int cur = (T & 1) * 16384;
        const int nxt = cur ^ 16384;

        // prefetch next tile first (drained only at the barrier below,
        // after the full MFMA phase)
        if (T + 1 < NT) {
            const size_t gko = (size_t)(T + 1) * 1024;
#pragma unroll
            for (int r = 0; r < 2; ++r) {
                async_copy16(ag[r] + gko, As + nxt + slo[r]);
                async_copy16(bg[r] + gko, Bs + nxt + slo[r]);
            }
        }

        int4v af[4], bf[8];
#pragma unroll
        for (int i = 0; i < 4; ++i)
            af[i] = *(const int4v*)(As + cur + a_off + i * 1024);
#pragma unroll
        for (int j = 0; j < 8; ++j)
            bf[j] = *(const int4v*)(Bs + cur + b_off + j * 1024);

#pragma unroll
        for (int i = 0; i < 4; ++i)
#pragma unroll
            for (int j = 0; j < 8; ++j)
                acc[i][j] = __builtin_amdgcn_mfma_i32_16x16x64_i8(af[i], bf[j],
                                                                  acc[i][j], 0, 0, 0);

        __syncthreads();
    }

    // --- epilogue: C/D layout col=lane&15, row=(lane>>4)*4+reg (verified)
    const int gcol0 = bn * 256 + pn0 * 16 + (lane & 15);
    float ac8[8];
#pragma unroll
    for (int j = 0; j < 8; ++j) ac8[j] = (float)acol[gcol0 + j * 16];

    const size_t grow0 = (size_t)bm * 256 + pm0 * 16 + (lane >> 4) * 4;
#pragma unroll
    for (int i = 0; i < 4; ++i) {
#pragma unroll
        for (int r = 0; r < 4; ++r) {
            const size_t row = grow0 + i * 16 + r;
            const float ar = (float)arow[row];
            _Float16* outp = Cout + row * (size_t)N_DIM + gcol0;
#pragma unroll
            for (int j = 0; j < 8; ++j) {
                float v = (float)acc[i][j][r] * ar * ac8[j];
                outp[j * 16] = (_Float16)v;
            }
        }
    }
}

// ---------------------------------------------------------------------------
extern "C" void kernel_launch(void* const* d_in, const int* in_sizes, int n_in,
                              void* d_out, int out_size, void* d_ws, size_t ws_size,
                              hipStream_t stream) {
    const int* a = (const int*)d_in[0];             // [M,K] int32 (int8 values)
    const int* b = (const int*)d_in[1];             // [N,K] int32 (int8 values)
    const _Float16* ar = (const _Float16*)d_in[2];  // [M] fp16
    const _Float16* ac = (const _Float16*)d_in[3];  // [N] fp16
    _Float16* out = (_Float16*)d_out;               // [M,N] fp16

    unsigned char* pa = (unsigned char*)d_ws;        // 16 MB
    unsigned char* pb = pa + (size_t)M_DIM * K_DIM;  // 32 MB

    const size_t total_frag = (size_t)(M_DIM / 16 + N_DIM / 16) * (K_DIM / 64) * 64;
    pack_frag<<<(int)(total_frag / 256), 256, 0, stream>>>(a, b, pa, pb);

    dim3 grid(N_DIM / 256, M_DIM / 256);
    gemm_i8<<<grid, 512, 0, stream>>>(pa, pb, ar, ac, out);
}